// Round 3
// baseline (58835.144 us; speedup 1.0000x reference)
//
#include <hip/hip_runtime.h>

#define TSTEPS 1920
#define NB 128
#define HIDN 256
#define LATN 128
#define EPSF 1e-5f

typedef __attribute__((ext_vector_type(8))) short bf16x8;
typedef __attribute__((ext_vector_type(4))) float f32x4;

__device__ __forceinline__ unsigned short f2bf(float x) {
    unsigned u = __builtin_bit_cast(unsigned, x);
    unsigned r = (u + 0x7fffu + ((u >> 16) & 1u)) >> 16;
    return (unsigned short)r;
}
__device__ __forceinline__ float bf2f(unsigned short h) {
    unsigned u = ((unsigned)h) << 16;
    return __builtin_bit_cast(float, u);
}
__device__ __forceinline__ float fsig(float x) {
    float e = __expf(-fabsf(x));
    float s = 1.f / (1.f + e);
    return x >= 0.f ? s : 1.f - s;
}
__device__ __forceinline__ float ftanh(float x) {
    float e = __expf(-2.f * fabsf(x));
    float r = (1.f - e) / (1.f + e);
    return x >= 0.f ? r : -r;
}
__device__ __forceinline__ float fleaky(float x) { return x > 0.f ? x : 0.2f * x; }

__device__ __forceinline__ bf16x8 bcast16(uint4 v) { return __builtin_bit_cast(bf16x8, v); }

// ---- pack W [N][KA+KB] -> MFMA B-fragment order, split hi/lo bf16 ----
// tile = nt*KT + kt ; elem e = tile*512 + l*8 + j ; n = nt*16+(l&15) ; k = kt*32+(l>>4)*8+j
__global__ void pack_bf16_frag(const float* __restrict__ A, const float* __restrict__ Bsrc,
                               int N, int KA, int KB,
                               unsigned short* __restrict__ hi, unsigned short* __restrict__ lo) {
    int e = blockIdx.x * 256 + threadIdx.x;
    int K = KA + KB;
    if (e >= N * K) return;
    int j = e & 7;
    int l = (e >> 3) & 63;
    int tile = e >> 9;
    int KT = K >> 5;
    int kt = tile % KT, nt = tile / KT;
    int n = nt * 16 + (l & 15);
    int k = kt * 32 + (l >> 4) * 8 + j;
    float v = (k < KA) ? A[n * KA + k] : Bsrc[n * KB + (k - KA)];
    unsigned short h = f2bf(v);
    hi[e] = h;
    lo[e] = f2bf(v - bf2f(h));
}

// ---- pack fp32 [N][K] -> [k4][n][4] for xw0 GEMV ----
__global__ void pack4T(const float* __restrict__ W, int N, int K, float* __restrict__ out) {
    int e = blockIdx.x * 256 + threadIdx.x;
    if (e >= N * K) return;
    int j = e & 3;
    int rest = e >> 2;
    int n = rest % N;
    int k4 = rest / N;
    out[e] = W[n * K + 4 * k4 + j];
}

__global__ void prep_b1(const float* __restrict__ bih1, const float* __restrict__ bhh1,
                        float* __restrict__ b1sum) {
    int i = blockIdx.x * 256 + threadIdx.x;
    if (i < 1024) b1sum[i] = bih1[i] + bhh1[i];
}

// ---- np head: embedding + MLP + LN + leaky -> x_const [B][512] ----
__global__ void np_head(const float* __restrict__ z, const int* __restrict__ labels,
                        const float* __restrict__ emb_W, const float* __restrict__ np_W,
                        const float* __restrict__ np_b, const float* __restrict__ np_g,
                        const float* __restrict__ np_be, float* __restrict__ x_const) {
    int b = blockIdx.x;
    int j = threadIdx.x;  // 0..255
    __shared__ float xc[LATN + HIDN];
    __shared__ float red[8];
    int lab = labels[b];
    if (j < LATN) xc[j] = z[b * LATN + j];
    float e = emb_W[lab * HIDN + j];
    xc[LATN + j] = e;
    __syncthreads();
    float d = np_b[j];
    for (int k = 0; k < LATN + HIDN; ++k) d += xc[k] * np_W[j * (LATN + HIDN) + k];
    int lane = j & 63, wv = j >> 6;
    float s = d, s2 = d * d;
    for (int o = 1; o < 64; o <<= 1) { s += __shfl_xor(s, o); s2 += __shfl_xor(s2, o); }
    if (lane == 0) { red[wv] = s; red[4 + wv] = s2; }
    __syncthreads();
    float S = red[0] + red[1] + red[2] + red[3];
    float S2 = red[4] + red[5] + red[6] + red[7];
    float m = S * (1.f / 256.f);
    float var = S2 * (1.f / 256.f) - m * m;
    float h = fleaky((d - m) * rsqrtf(var + EPSF) * np_g[j] + np_be[j]);
    x_const[b * 512 + j] = h;
    x_const[b * 512 + 256 + j] = e;
}

// ---- xw0[b][g] = bih0+bhh0 + x_const[b] . Wih0[g]  (fp32) ----
__global__ void __launch_bounds__(1024) xw0_kernel(const float* __restrict__ x_const,
                                                   const float4* __restrict__ Wih0T4,
                                                   const float* __restrict__ bih0,
                                                   const float* __restrict__ bhh0,
                                                   float* __restrict__ xw0) {
    int b = blockIdx.x;
    int g = threadIdx.x;
    __shared__ float xc[512];
    if (g < 512) xc[g] = x_const[b * 512 + g];
    __syncthreads();
    const float4* xc4 = (const float4*)xc;
    float4 acc = {0.f, 0.f, 0.f, 0.f};
#pragma unroll 8
    for (int k4 = 0; k4 < 128; ++k4) {
        float4 w = Wih0T4[k4 * 1024 + g];
        float4 x = xc4[k4];
        acc.x = fmaf(w.x, x.x, acc.x);
        acc.y = fmaf(w.y, x.y, acc.y);
        acc.z = fmaf(w.z, x.z, acc.z);
        acc.w = fmaf(w.w, x.w, acc.w);
    }
    xw0[b * 1024 + g] = bih0[g] + bhh0[g] + ((acc.x + acc.y) + (acc.z + acc.w));
}

#define MFMA(a, b, c) __builtin_amdgcn_mfma_f32_16x16x32_bf16((a), (b), (c), 0, 0, 0)

// ---- fused 2-layer LSTM + per-step head via MFMA. 8 blocks x 512 thr x 16 rows ----
__global__ void __launch_bounds__(512) lstm_mfma(
    const uint4* __restrict__ whh0h, const uint4* __restrict__ whh0l,
    const uint4* __restrict__ w1h, const uint4* __restrict__ w1l,
    const uint4* __restrict__ sw1h, const uint4* __restrict__ sw1l,
    const float* __restrict__ xw0g, const float* __restrict__ b1sum,
    const float* __restrict__ sb1, const float* __restrict__ sg,
    const float* __restrict__ sbe, const float* __restrict__ sW2,
    const float* __restrict__ sb2, float* __restrict__ base_out,
    float* __restrict__ hsum_out) {
    const int b = blockIdx.x;
    const int b16 = b * 16;
    const int tid = threadIdx.x;  // 0..511
    const int l = tid & 63;
    const int w = tid >> 6;       // wave 0..7
    const int ln16 = l & 15;
    const int kg = l >> 4;        // 0..3

    __shared__ unsigned short hhi[16 * 512];  // [row][k] bf16 hi, 16KB, XOR-swizzled
    __shared__ unsigned short hlo[16 * 512];  // lo, 16KB
    __shared__ float s1b[16 * 132];           // head pre-LN, padded stride

    // zero h state
    for (int i = tid; i < 16 * 512; i += 512) { hhi[i] = 0; hlo[i] = 0; }

    char* hhiB = (char*)hhi;
    char* hloB = (char*)hlo;
    const int abase = ln16 * 1024;
    const int aswz = (ln16 & 7) << 4;
    const int kgo = kg * 16;

    // hoisted constants
    f32x4 xw0i[8];
    float b1v[8];
#pragma unroll
    for (int q = 0; q < 8; ++q) {
        int nt = 2 * w + 16 * (q >> 1) + (q & 1);
        int n = nt * 16 + ln16;
        b1v[q] = b1sum[n];
#pragma unroll
        for (int r = 0; r < 4; ++r) xw0i[q][r] = xw0g[(b16 + kg * 4 + r) * 1024 + n];
    }
    float sb1v = sb1[w * 16 + ln16];
    // LN lane constants (cols 2l, 2l+1)
    float sg0 = sg[2 * l], sg1 = sg[2 * l + 1];
    float sbe0 = sbe[2 * l], sbe1 = sbe[2 * l + 1];
    float sw20 = sW2[2 * l], sw21 = sW2[2 * l + 1];
    float sb2v = sb2[0];

    float c0[8], c1[8], hs[8];
#pragma unroll
    for (int i = 0; i < 8; ++i) { c0[i] = 0.f; c1[i] = 0.f; hs[i] = 0.f; }

    __syncthreads();

#pragma unroll 1
    for (int t = 0; t < TSTEPS; ++t) {
        // ---------- MV0: gates0 = xw0 + Whh0 @ h0 ----------
        f32x4 acc[8];
#pragma unroll
        for (int q = 0; q < 8; ++q) acc[q] = xw0i[q];
#pragma unroll 2
        for (int kt = 0; kt < 8; ++kt) {
            int aoff = abase + ((kt * 64 + kgo) ^ aswz);
            bf16x8 ahi = bcast16(*(const uint4*)(hhiB + aoff));
            bf16x8 alo = bcast16(*(const uint4*)(hloB + aoff));
#pragma unroll
            for (int q = 0; q < 8; ++q) {
                int nt = 2 * w + 16 * (q >> 1) + (q & 1);
                int idx = (nt * 8 + kt) * 64 + l;
                bf16x8 bhi = bcast16(whh0h[idx]);
                bf16x8 blo = bcast16(whh0l[idx]);
                acc[q] = MFMA(ahi, bhi, acc[q]);
                acc[q] = MFMA(alo, bhi, acc[q]);
                acc[q] = MFMA(ahi, blo, acc[q]);
            }
        }
        __syncthreads();  // (a) h0 reads done everywhere
        // ---------- UPD0 (in-register) + write h0 ----------
#pragma unroll
        for (int s = 0; s < 2; ++s) {
#pragma unroll
            for (int r = 0; r < 4; ++r) {
                float i_ = acc[s][r], f_ = acc[2 + s][r], g_ = acc[4 + s][r], o_ = acc[6 + s][r];
                float c = fsig(f_) * c0[s * 4 + r] + fsig(i_) * ftanh(g_);
                c0[s * 4 + r] = c;
                float h = fsig(o_) * ftanh(c);
                int u = 32 * w + 16 * s + ln16;
                int m = kg * 4 + r;
                int off = m * 1024 + ((2 * u) ^ ((m & 7) << 4));
                unsigned short hh = f2bf(h);
                *(unsigned short*)(hhiB + off) = hh;
                *(unsigned short*)(hloB + off) = f2bf(h - bf2f(hh));
            }
        }
        __syncthreads();  // (b) h0 new visible
        // ---------- MV1: gates1 = b1 + [Wih1|Whh1] @ [h0;h1] ----------
#pragma unroll
        for (int q = 0; q < 8; ++q) {
            float bv = b1v[q];
            acc[q] = (f32x4){bv, bv, bv, bv};
        }
#pragma unroll 2
        for (int kt = 0; kt < 16; ++kt) {
            int aoff = abase + ((kt * 64 + kgo) ^ aswz);
            bf16x8 ahi = bcast16(*(const uint4*)(hhiB + aoff));
            bf16x8 alo = bcast16(*(const uint4*)(hloB + aoff));
#pragma unroll
            for (int q = 0; q < 8; ++q) {
                int nt = 2 * w + 16 * (q >> 1) + (q & 1);
                int idx = (nt * 16 + kt) * 64 + l;
                bf16x8 bhi = bcast16(w1h[idx]);
                bf16x8 blo = bcast16(w1l[idx]);
                acc[q] = MFMA(ahi, bhi, acc[q]);
                acc[q] = MFMA(alo, bhi, acc[q]);
                acc[q] = MFMA(ahi, blo, acc[q]);
            }
        }
        __syncthreads();  // (c) h0/h1 reads done
        // ---------- UPD1 + write h1 + hsum ----------
#pragma unroll
        for (int s = 0; s < 2; ++s) {
#pragma unroll
            for (int r = 0; r < 4; ++r) {
                float i_ = acc[s][r], f_ = acc[2 + s][r], g_ = acc[4 + s][r], o_ = acc[6 + s][r];
                float c = fsig(f_) * c1[s * 4 + r] + fsig(i_) * ftanh(g_);
                c1[s * 4 + r] = c;
                float h = fsig(o_) * ftanh(c);
                hs[s * 4 + r] += h;
                int u = 32 * w + 16 * s + ln16;
                int m = kg * 4 + r;
                int off = m * 1024 + ((512 + 2 * u) ^ ((m & 7) << 4));
                unsigned short hh = f2bf(h);
                *(unsigned short*)(hhiB + off) = hh;
                *(unsigned short*)(hloB + off) = f2bf(h - bf2f(hh));
            }
        }
        __syncthreads();  // (d) h1 new visible
        // ---------- HEAD MFMA: s1 = sb1 + sW1 @ h1 (N=128, K=256) ----------
        {
            f32x4 a1 = (f32x4){sb1v, sb1v, sb1v, sb1v};
#pragma unroll 2
            for (int kt = 0; kt < 8; ++kt) {
                int aoff = abase + 512 + ((kt * 64 + kgo) ^ aswz);
                bf16x8 ahi = bcast16(*(const uint4*)(hhiB + aoff));
                bf16x8 alo = bcast16(*(const uint4*)(hloB + aoff));
                int idx = (w * 8 + kt) * 64 + l;
                bf16x8 bhi = bcast16(sw1h[idx]);
                bf16x8 blo = bcast16(sw1l[idx]);
                a1 = MFMA(ahi, bhi, a1);
                a1 = MFMA(alo, bhi, a1);
                a1 = MFMA(ahi, blo, a1);
            }
#pragma unroll
            for (int r = 0; r < 4; ++r) s1b[(kg * 4 + r) * 132 + w * 16 + ln16] = a1[r];
        }
        __syncthreads();  // (e) s1 complete
        // ---------- LN(128) + leaky + dot sW2 + tanh -> base_out (2 rows/wave) ----------
#pragma unroll
        for (int rr = 0; rr < 2; ++rr) {
            int row = 2 * w + rr;
            float2 v = *(const float2*)&s1b[row * 132 + 2 * l];
            float ssum = v.x + v.y, ssq = v.x * v.x + v.y * v.y;
#pragma unroll
            for (int o = 1; o < 64; o <<= 1) { ssum += __shfl_xor(ssum, o); ssq += __shfl_xor(ssq, o); }
            float m = ssum * (1.f / 128.f);
            float var = ssq * (1.f / 128.f) - m * m;
            float rstd = rsqrtf(var + EPSF);
            float p0 = fleaky((v.x - m) * rstd * sg0 + sbe0);
            float p1 = fleaky((v.y - m) * rstd * sg1 + sbe1);
            float q = p0 * sw20 + p1 * sw21;
#pragma unroll
            for (int o = 1; o < 64; o <<= 1) q += __shfl_xor(q, o);
            if (l == 0) base_out[(b16 + row) * TSTEPS + t] = ftanh(q + sb2v);
        }
        // no sync needed here: next-step MV0 reads h0 (untouched since (b));
        // s1b next written only after (d') of next step.
    }
    // hsum out
#pragma unroll
    for (int s = 0; s < 2; ++s)
#pragma unroll
        for (int r = 0; r < 4; ++r)
            hsum_out[(b16 + kg * 4 + r) * HIDN + 32 * w + 16 * s + ln16] = hs[s * 4 + r];
}

// ---- final head + oscillator + smoothing + label select ----
__global__ void out_kernel(const float* __restrict__ hsum, const float* __restrict__ oW1,
                           const float* __restrict__ ob1, const float* __restrict__ og,
                           const float* __restrict__ obe, const float* __restrict__ oW2,
                           const float* __restrict__ ob2, const float* __restrict__ base,
                           const int* __restrict__ labels, const float* __restrict__ stress_w,
                           const float* __restrict__ amu_w, const float* __restrict__ amu_b,
                           float* __restrict__ out) {
    int b = blockIdx.x;
    int tid = threadIdx.x;  // 0..255
    int lane = tid & 63, wv = tid >> 6;
    __shared__ float havg[256];
    __shared__ float red[8];
    __shared__ float params[3];
    __shared__ float e_row[TSTEPS];
    havg[tid] = hsum[b * 256 + tid] * (1.f / (float)TSTEPS);
    __syncthreads();
    float d1 = 0.f;
    if (tid < 128) {
        d1 = ob1[tid];
        for (int k = 0; k < 256; ++k) d1 += havg[k] * oW1[tid * 256 + k];
    }
    float s = d1, s2 = d1 * d1;
    for (int o = 1; o < 64; o <<= 1) { s += __shfl_xor(s, o); s2 += __shfl_xor(s2, o); }
    if (lane == 0 && wv < 2) { red[wv] = s; red[2 + wv] = s2; }
    __syncthreads();
    float m = (red[0] + red[1]) * (1.f / 128.f);
    float var = (red[2] + red[3]) * (1.f / 128.f) - m * m;
    float rstd = rsqrtf(var + EPSF);
    float p = 0.f;
    if (tid < 128) p = fleaky((d1 - m) * rstd * og[tid] + obe[tid]);
    float q0 = tid < 128 ? p * oW2[0 * 128 + tid] : 0.f;
    float q1 = tid < 128 ? p * oW2[1 * 128 + tid] : 0.f;
    float q2 = tid < 128 ? p * oW2[2 * 128 + tid] : 0.f;
    for (int o = 1; o < 64; o <<= 1) {
        q0 += __shfl_xor(q0, o); q1 += __shfl_xor(q1, o); q2 += __shfl_xor(q2, o);
    }
    __syncthreads();
    if (lane == 0 && wv < 2) { red[wv] = q0; red[2 + wv] = q1; red[4 + wv] = q2; }
    __syncthreads();
    if (tid == 0) {
        float op0 = red[0] + red[1] + ob2[0];
        float op1 = red[2] + red[3] + ob2[1];
        float op2 = red[4] + red[5] + ob2[2];
        params[0] = 0.23f + 0.04f * ftanh(op0);
        params[1] = 2.0f + 1.5f * ftanh(op1);
        params[2] = 3.14159265358979f * fsig(op2);
    }
    __syncthreads();
    float freq = params[0], amp = params[1], ph = params[2];
    for (int t = tid; t < TSTEPS; t += 256) {
        float x = freq * ((float)TSTEPS * (float)t / (float)(TSTEPS - 1));
        x -= floorf(x);
        float osc = amp * __sinf(6.28318530717958647f * x + ph);
        e_row[t] = 0.6f * base[b * TSTEPS + t] + 0.4f * osc;
    }
    __syncthreads();
    int lab = labels[b];
    float sw = stress_w[0];
    float w0 = amu_w[0], w1 = amu_w[1], w2 = amu_w[2], ab = amu_b[0];
    for (int t = tid; t < TSTEPS; t += 256) {
        float e = e_row[t];
        float r;
        if (lab == 1) r = e;
        else if (lab == 2) r = sw * e;
        else if (lab == 3) {
            float em = t > 0 ? e_row[t - 1] : 0.f;
            float ep = t < TSTEPS - 1 ? e_row[t + 1] : 0.f;
            r = w0 * em + w1 * e + w2 * ep + ab;
        } else r = 0.f;
        out[b * TSTEPS + t] = r;
    }
}

extern "C" void kernel_launch(void* const* d_in, const int* in_sizes, int n_in,
                              void* d_out, int out_size, void* d_ws, size_t ws_size,
                              hipStream_t stream) {
    (void)in_sizes; (void)n_in; (void)out_size; (void)ws_size;
    const float* z      = (const float*)d_in[0];
    const int* labels   = (const int*)d_in[1];
    const float* emb_W  = (const float*)d_in[2];
    const float* np_W   = (const float*)d_in[3];
    const float* np_b   = (const float*)d_in[4];
    const float* np_g   = (const float*)d_in[5];
    const float* np_be  = (const float*)d_in[6];
    const float* Wih0   = (const float*)d_in[7];
    const float* Whh0   = (const float*)d_in[8];
    const float* bih0   = (const float*)d_in[9];
    const float* bhh0   = (const float*)d_in[10];
    const float* Wih1   = (const float*)d_in[11];
    const float* Whh1   = (const float*)d_in[12];
    const float* bih1   = (const float*)d_in[13];
    const float* bhh1   = (const float*)d_in[14];
    const float* oW1    = (const float*)d_in[15];
    const float* ob1    = (const float*)d_in[16];
    const float* og     = (const float*)d_in[17];
    const float* obe    = (const float*)d_in[18];
    const float* oW2    = (const float*)d_in[19];
    const float* ob2    = (const float*)d_in[20];
    const float* sW1    = (const float*)d_in[21];
    const float* sb1    = (const float*)d_in[22];
    const float* sg     = (const float*)d_in[23];
    const float* sbe    = (const float*)d_in[24];
    const float* sW2    = (const float*)d_in[25];
    const float* sb2    = (const float*)d_in[26];
    const float* stressw= (const float*)d_in[27];
    const float* amu_w  = (const float*)d_in[28];
    const float* amu_b  = (const float*)d_in[29];
    float* out = (float*)d_out;

    uint8_t* ws = (uint8_t*)d_ws;
    size_t off = 0;
    unsigned short* whh0h = (unsigned short*)(ws + off); off += (size_t)1024 * 256 * 2;  // 512KB
    unsigned short* whh0l = (unsigned short*)(ws + off); off += (size_t)1024 * 256 * 2;
    unsigned short* w1h   = (unsigned short*)(ws + off); off += (size_t)1024 * 512 * 2;  // 1MB
    unsigned short* w1l   = (unsigned short*)(ws + off); off += (size_t)1024 * 512 * 2;
    unsigned short* sw1h  = (unsigned short*)(ws + off); off += (size_t)128 * 256 * 2;   // 64KB
    unsigned short* sw1l  = (unsigned short*)(ws + off); off += (size_t)128 * 256 * 2;
    float* Wih0T4 = (float*)(ws + off); off += (size_t)1024 * 512 * 4;                   // 2MB
    float* x_const= (float*)(ws + off); off += (size_t)NB * 512 * 4;
    float* xw0    = (float*)(ws + off); off += (size_t)NB * 1024 * 4;
    float* b1sum  = (float*)(ws + off); off += (size_t)1024 * 4;
    float* hsum   = (float*)(ws + off); off += (size_t)NB * 256 * 4;
    float* basef  = (float*)(ws + off); off += (size_t)NB * TSTEPS * 4;

    pack_bf16_frag<<<1024, 256, 0, stream>>>(Whh0, nullptr, 1024, 256, 0, whh0h, whh0l);
    pack_bf16_frag<<<2048, 256, 0, stream>>>(Wih1, Whh1, 1024, 256, 256, w1h, w1l);
    pack_bf16_frag<<<128, 256, 0, stream>>>(sW1, nullptr, 128, 256, 0, sw1h, sw1l);
    pack4T<<<2048, 256, 0, stream>>>(Wih0, 1024, 512, Wih0T4);
    prep_b1<<<4, 256, 0, stream>>>(bih1, bhh1, b1sum);

    np_head<<<NB, 256, 0, stream>>>(z, labels, emb_W, np_W, np_b, np_g, np_be, x_const);
    xw0_kernel<<<NB, 1024, 0, stream>>>(x_const, (const float4*)Wih0T4, bih0, bhh0, xw0);
    lstm_mfma<<<8, 512, 0, stream>>>((const uint4*)whh0h, (const uint4*)whh0l,
                                     (const uint4*)w1h, (const uint4*)w1l,
                                     (const uint4*)sw1h, (const uint4*)sw1l,
                                     xw0, b1sum, sb1, sg, sbe, sW2, sb2, basef, hsum);
    out_kernel<<<NB, 256, 0, stream>>>(hsum, oW1, ob1, og, obe, oW2, ob2, basef, labels,
                                       stressw, amu_w, amu_b, out);
}